// Round 3
// baseline (274.170 us; speedup 1.0000x reference)
//
#include <hip/hip_runtime.h>
#include <hip/hip_bf16.h>
#include <float.h>

#define B_    16
#define N1_   4096
#define N2_   1024
#define C2_   256
#define OUT_  256
#define K_    4096   // GEMM K == N1

typedef short short8 __attribute__((ext_vector_type(8)));
typedef float float4v __attribute__((ext_vector_type(4)));

static __device__ __forceinline__ unsigned short f32_to_bf16_bits(float v) {
    __hip_bfloat16 h = __float2bfloat16(v);
    return *(unsigned short*)&h;
}

// ---------------------------------------------------------------------------
// Kernel 0: convert W1 f32 -> bf16 (1,048,576 elems) for the MFMA GEMM.
// ---------------------------------------------------------------------------
__global__ __launch_bounds__(256) void w1cvt_kernel(
    const float* __restrict__ W1, unsigned short* __restrict__ W1b)
{
    const int i = (blockIdx.x * 256 + threadIdx.x) * 4;
    float4 v = *(const float4*)(W1 + i);
    ushort4 o;
    o.x = f32_to_bf16_bits(v.x);
    o.y = f32_to_bf16_bits(v.y);
    o.z = f32_to_bf16_bits(v.z);
    o.w = f32_to_bf16_bits(v.w);
    *(ushort4*)(W1b + i) = o;
}

// ---------------------------------------------------------------------------
// Kernel 1: for each (b, n1): distances to all 1024 xyz2 points, top-3
// smallest (ref tie-break: earliest index), inverse-distance weights.
// One thread per n1 point; xyz2[b] staged in LDS as float4 (x,y,z,|q|^2).
// ---------------------------------------------------------------------------
__global__ __launch_bounds__(256) void knn_kernel(
    const float* __restrict__ xyz1,
    const float* __restrict__ xyz2,
    float* __restrict__ wgt, int* __restrict__ idx_out)
{
    __shared__ float4 pts[N2_];
    const int b = blockIdx.y;
    const int t = threadIdx.x;

    for (int r = 0; r < 4; ++r) {
        int j = r * 256 + t;
        const float* p = xyz2 + ((size_t)b * N2_ + j) * 3;
        float x = p[0], y = p[1], z = p[2];
        float dd = (x * x + y * y) + z * z;   // ref order: sum over c
        pts[j] = make_float4(x, y, z, dd);
    }
    __syncthreads();

    const int n1 = blockIdx.x * 256 + t;
    const float* q = xyz1 + ((size_t)b * N1_ + n1) * 3;
    float s0 = q[0], s1 = q[1], s2 = q[2];
    float ss = (s0 * s0 + s1 * s1) + s2 * s2;

    float d0 = FLT_MAX, d1 = FLT_MAX, d2 = FLT_MAX;
    int i0 = 0, i1 = 0, i2 = 0;

    #pragma unroll 4
    for (int j = 0; j < N2_; ++j) {
        float4 pq = pts[j];
        float dot = (s0 * pq.x + s1 * pq.y) + s2 * pq.z;
        float d = (-2.0f * dot + ss) + pq.w;   // ref: (-2*einsum + ss) + dd
        if (d < d2) {
            if (d < d1) {
                if (d < d0) { d2 = d1; i2 = i1; d1 = d0; i1 = i0; d0 = d; i0 = j; }
                else        { d2 = d1; i2 = i1; d1 = d;  i1 = j; }
            } else          { d2 = d;  i2 = j; }
        }
    }

    float r0 = 1.0f / (d0 + 1e-8f);
    float r1 = 1.0f / (d1 + 1e-8f);
    float r2 = 1.0f / (d2 + 1e-8f);
    float s  = (r0 + r1) + r2;
    size_t base = ((size_t)b * N1_ + n1) * 3;
    wgt[base + 0] = r0 / s;  wgt[base + 1] = r1 / s;  wgt[base + 2] = r2 / s;
    idx_out[base + 0] = i0;  idx_out[base + 1] = i1;  idx_out[base + 2] = i2;
}

// ---------------------------------------------------------------------------
// Kernel 2: interp_t[b][c][n] = sum_k w_k * x2[b][idx_k][c], written
// K-major (n contiguous, bf16) via an LDS transpose so the GEMM's B operand
// stages with plain vector copies.
// Block: 256 threads = 4 waves, handles 64 n-points x all 256 channels.
// ---------------------------------------------------------------------------
#define TPAD 65
__global__ __launch_bounds__(256) void interp_kernel(
    const float* __restrict__ x2,
    const float* __restrict__ wgt, const int* __restrict__ idx,
    unsigned short* __restrict__ interp_t)
{
    __shared__ unsigned short tile[C2_][TPAD];   // [c][n_local]
    const int b = blockIdx.y;
    const int n0 = blockIdx.x * 64;
    const int t = threadIdx.x;
    const int w = t >> 6;     // wave id 0..3
    const int l = t & 63;     // lane

    for (int p = 0; p < 16; ++p) {
        int nl = p * 4 + w;
        size_t base = ((size_t)b * N1_ + (n0 + nl)) * 3;
        float w0 = wgt[base], w1 = wgt[base + 1], w2 = wgt[base + 2];
        int i0 = idx[base], i1 = idx[base + 1], i2 = idx[base + 2];
        // lane l covers channels 4l..4l+3 of each gathered row (1 KB rows)
        const float4 va = ((const float4*)(x2 + ((size_t)b * N2_ + i0) * C2_))[l];
        const float4 vb = ((const float4*)(x2 + ((size_t)b * N2_ + i1) * C2_))[l];
        const float4 vc = ((const float4*)(x2 + ((size_t)b * N2_ + i2) * C2_))[l];
        float fa[4] = {va.x, va.y, va.z, va.w};
        float fb[4] = {vb.x, vb.y, vb.z, vb.w};
        float fc[4] = {vc.x, vc.y, vc.z, vc.w};
        #pragma unroll
        for (int i = 0; i < 4; ++i) {
            float v = w0 * fa[i];
            v = fmaf(w1, fb[i], v);
            v = fmaf(w2, fc[i], v);
            tile[l * 4 + i][nl] = f32_to_bf16_bits(v);
        }
    }
    __syncthreads();

    for (int r = 0; r < 64; ++r) {
        int c = r * 4 + w;
        interp_t[((size_t)b * C2_ + c) * K_ + n0 + l] = tile[c][l];
    }
}

// ---------------------------------------------------------------------------
// Kernel 3: per-batch GEMM  Z[b][o][c] = sum_n W1[o][n]*interp_t[b][c][n] + b1[o]
// MFMA 16x16x32 bf16. Tile 64(o) x 64(c), BK=32, 4 waves each own a 32x32
// quadrant (2x2 MFMA frags). LDS rows padded to 40 elems (80B).
// ---------------------------------------------------------------------------
#define LDA 40
__global__ __launch_bounds__(256) void gemm_kernel(
    const unsigned short* __restrict__ W1b,
    const float* __restrict__ b1,
    const unsigned short* __restrict__ interp_t,
    float* __restrict__ Z)
{
    __shared__ unsigned short Alds[64][LDA];
    __shared__ unsigned short Blds[64][LDA];
    const int b  = blockIdx.z;
    const int o0 = blockIdx.y * 64;
    const int c0 = blockIdx.x * 64;
    const int t = threadIdx.x;
    const int w = t >> 6, l = t & 63;
    const int row = t >> 2, q = t & 3;        // staging: 4 threads per row
    const int ob = (w >> 1) * 32, cb = (w & 1) * 32;
    const int m = l & 15, kq = l >> 4;

    const unsigned short* Wp = W1b + (size_t)(o0 + row) * K_ + q * 8;
    const unsigned short* Bp = interp_t + ((size_t)b * C2_ + (c0 + row)) * K_ + q * 8;

    float4v acc[2][2] = {};

    for (int kk = 0; kk < K_; kk += 32) {
        uint4 av = *(const uint4*)(Wp + kk);
        uint4 bv = *(const uint4*)(Bp + kk);
        *(uint4*)&Alds[row][q * 8] = av;
        *(uint4*)&Blds[row][q * 8] = bv;
        __syncthreads();
        short8 a0 = *(const short8*)&Alds[ob + m][kq * 8];
        short8 a1 = *(const short8*)&Alds[ob + 16 + m][kq * 8];
        short8 b0 = *(const short8*)&Blds[cb + m][kq * 8];
        short8 b1f = *(const short8*)&Blds[cb + 16 + m][kq * 8];
        acc[0][0] = __builtin_amdgcn_mfma_f32_16x16x32_bf16(a0, b0,  acc[0][0], 0, 0, 0);
        acc[0][1] = __builtin_amdgcn_mfma_f32_16x16x32_bf16(a0, b1f, acc[0][1], 0, 0, 0);
        acc[1][0] = __builtin_amdgcn_mfma_f32_16x16x32_bf16(a1, b0,  acc[1][0], 0, 0, 0);
        acc[1][1] = __builtin_amdgcn_mfma_f32_16x16x32_bf16(a1, b1f, acc[1][1], 0, 0, 0);
        __syncthreads();
    }

    // C/D layout (m89-verified): col = lane&15 (c), row = (lane>>4)*4 + r (o)
    #pragma unroll
    for (int mi = 0; mi < 2; ++mi)
    #pragma unroll
    for (int ni = 0; ni < 2; ++ni)
    #pragma unroll
    for (int r = 0; r < 4; ++r) {
        int o = o0 + ob + mi * 16 + kq * 4 + r;
        int c = c0 + cb + ni * 16 + m;
        Z[((size_t)b * OUT_ + o) * C2_ + c] = acc[mi][ni][r] + b1[o];
    }
}

// ---------------------------------------------------------------------------
// Kernel 4: BN stats — per channel c, sum and sumsq over (b,o) via atomics.
// ---------------------------------------------------------------------------
__global__ __launch_bounds__(256) void stats_kernel(
    const float* __restrict__ Z, float* __restrict__ accum)
{
    const int b  = blockIdx.x >> 2;
    const int oq = blockIdx.x & 3;
    const int c  = threadIdx.x;
    float s = 0.0f, s2 = 0.0f;
    for (int o = 0; o < 64; ++o) {
        float v = Z[((size_t)b * OUT_ + oq * 64 + o) * C2_ + c];
        s += v; s2 += v * v;
    }
    atomicAdd(&accum[c], s);
    atomicAdd(&accum[C2_ + c], s2);
}

// ---------------------------------------------------------------------------
// Kernel 5: normalize + affine + ReLU + f32 store. out has same layout as Z.
// ---------------------------------------------------------------------------
__global__ __launch_bounds__(256) void bn_kernel(
    const float* __restrict__ Z, const float* __restrict__ accum,
    const float* __restrict__ gamma, const float* __restrict__ beta,
    float* __restrict__ out)
{
    const int i = (blockIdx.x * 256 + threadIdx.x) * 4;
    float4 z = *(const float4*)(Z + i);
    float vals[4] = {z.x, z.y, z.z, z.w};
    const int cb = i & 255;
    float res[4];
    #pragma unroll
    for (int j = 0; j < 4; ++j) {
        int c = cb + j;
        float mean = accum[c] * (1.0f / 4096.0f);
        float var  = accum[C2_ + c] * (1.0f / 4096.0f) - mean * mean;
        float rstd = 1.0f / sqrtf(var + 1e-5f);
        float v = gamma[c] * ((vals[j] - mean) * rstd) + beta[c];
        res[j] = fmaxf(v, 0.0f);
    }
    *(float4*)(out + i) = make_float4(res[0], res[1], res[2], res[3]);
}

// ---------------------------------------------------------------------------
extern "C" void kernel_launch(void* const* d_in, const int* in_sizes, int n_in,
                              void* d_out, int out_size, void* d_ws, size_t ws_size,
                              hipStream_t stream) {
    // inputs (setup_inputs order, all float32):
    //   x1(unused), x2, xyz1, xyz2, W1, b1, gamma, beta
    const float* x2    = (const float*)d_in[1];
    const float* xyz1  = (const float*)d_in[2];
    const float* xyz2  = (const float*)d_in[3];
    const float* W1    = (const float*)d_in[4];
    const float* b1    = (const float*)d_in[5];
    const float* gamma = (const float*)d_in[6];
    const float* beta  = (const float*)d_in[7];

    char* ws = (char*)d_ws;
    float*          wgt      = (float*)(ws);                       //   786,432 B
    int*            idx      = (int*)(ws + 786432);                //   786,432 B
    unsigned short* interp_t = (unsigned short*)(ws + 1572864);    // 33,554,432 B
    unsigned short* W1b      = (unsigned short*)(ws + 35127296);   //  2,097,152 B
    float*          Z        = (float*)(ws + 37224448);            //  4,194,304 B
    float*          accum    = (float*)(ws + 41418752);            //      2,048 B

    (void)hipMemsetAsync(accum, 0, 512 * sizeof(float), stream);

    w1cvt_kernel <<<1024, 256, 0, stream>>>(W1, W1b);
    knn_kernel   <<<dim3(16, 16), 256, 0, stream>>>(xyz1, xyz2, wgt, idx);
    interp_kernel<<<dim3(64, 16), 256, 0, stream>>>(x2, wgt, idx, interp_t);
    gemm_kernel  <<<dim3(4, 4, 16), 256, 0, stream>>>(W1b, b1, interp_t, Z);
    stats_kernel <<<64, 256, 0, stream>>>(Z, accum);
    bn_kernel    <<<1024, 256, 0, stream>>>(Z, accum, gamma, beta,
                                            (float*)d_out);
}

// Round 4
// 212.220 us; speedup vs baseline: 1.2919x; 1.2919x over previous
//
#include <hip/hip_runtime.h>
#include <hip/hip_bf16.h>
#include <float.h>

#define B_    16
#define N1_   4096
#define N2_   1024
#define C2_   256
#define OUT_  256
#define K_    4096   // GEMM K == N1

typedef short short8 __attribute__((ext_vector_type(8)));
typedef float float4v __attribute__((ext_vector_type(4)));

static __device__ __forceinline__ unsigned short f32_to_bf16_bits(float v) {
    __hip_bfloat16 h = __float2bfloat16(v);
    return *(unsigned short*)&h;
}

// ---------------------------------------------------------------------------
// Kernel 0: convert W1 f32 -> bf16 (1,048,576 elems) for the MFMA GEMM.
// ---------------------------------------------------------------------------
__global__ __launch_bounds__(256) void w1cvt_kernel(
    const float* __restrict__ W1, unsigned short* __restrict__ W1b)
{
    const int i = (blockIdx.x * 256 + threadIdx.x) * 4;
    float4 v = *(const float4*)(W1 + i);
    ushort4 o;
    o.x = f32_to_bf16_bits(v.x);
    o.y = f32_to_bf16_bits(v.y);
    o.z = f32_to_bf16_bits(v.z);
    o.w = f32_to_bf16_bits(v.w);
    *(ushort4*)(W1b + i) = o;
}

// ---------------------------------------------------------------------------
// Kernel 1 (rewritten): top-3 NN + inverse-distance weights.
// Block = 64 n1 points x 4 waves; wave w scans candidate quarter
// [256w, 256w+256) keeping a branchless per-thread top-3 on the monotone
// key f = 0.5*|p|^2 - dot(q,p)  (d = ss + 2f). Blocked (not interleaved)
// split so strict '<' preserves earliest-index tie-break across the merge.
// Grid 64x16 = 1024 blocks -> 4 blocks/CU, 4 waves/SIMD.
// ---------------------------------------------------------------------------
__global__ __launch_bounds__(256) void knn_kernel(
    const float* __restrict__ xyz1,
    const float* __restrict__ xyz2,
    float* __restrict__ wgt, int* __restrict__ idx_out)
{
    __shared__ float4 pts[N2_];          // (x, y, z, 0.5*|p|^2)
    __shared__ float  pf[4][64][3];
    __shared__ int    pi[4][64][3];

    const int b  = blockIdx.y;
    const int n0 = blockIdx.x * 64;
    const int t  = threadIdx.x;
    const int w  = t >> 6;   // wave id == candidate-quarter id
    const int l  = t & 63;   // local n1

    for (int r = 0; r < 4; ++r) {
        int j = r * 256 + t;
        const float* p = xyz2 + ((size_t)b * N2_ + j) * 3;
        float x = p[0], y = p[1], z = p[2];
        pts[j] = make_float4(x, y, z, 0.5f * ((x * x + y * y) + z * z));
    }
    __syncthreads();

    const int n1 = n0 + l;
    const float* q = xyz1 + ((size_t)b * N1_ + n1) * 3;
    const float s0 = q[0], s1 = q[1], s2 = q[2];

    float f0 = FLT_MAX, f1 = FLT_MAX, f2 = FLT_MAX;
    int   i0 = 0, i1 = 0, i2 = 0;
    const int jbase = w * 256;

    #pragma unroll 4
    for (int jj = 0; jj < 256; ++jj) {
        const int j = jbase + jj;
        float4 pq = pts[j];
        float dot = s0 * pq.x;
        dot = fmaf(s1, pq.y, dot);
        dot = fmaf(s2, pq.z, dot);
        float f = pq.w - dot;
        bool c0 = f < f0, c1 = f < f1, c2 = f < f2;
        f2 = c1 ? f1 : (c2 ? f : f2);  i2 = c1 ? i1 : (c2 ? j : i2);
        f1 = c0 ? f0 : (c1 ? f : f1);  i1 = c0 ? i0 : (c1 ? j : i1);
        f0 = c0 ? f  : f0;             i0 = c0 ? j  : i0;
    }

    pf[w][l][0] = f0; pf[w][l][1] = f1; pf[w][l][2] = f2;
    pi[w][l][0] = i0; pi[w][l][1] = i1; pi[w][l][2] = i2;
    __syncthreads();

    if (w == 0) {
        float g0 = FLT_MAX, g1 = FLT_MAX, g2 = FLT_MAX;
        int   j0 = 0, j1 = 0, j2 = 0;
        #pragma unroll
        for (int p = 0; p < 4; ++p)
        #pragma unroll
        for (int r = 0; r < 3; ++r) {
            float f = pf[p][l][r];
            int   j = pi[p][l][r];
            bool c0 = f < g0, c1 = f < g1, c2 = f < g2;
            g2 = c1 ? g1 : (c2 ? f : g2);  j2 = c1 ? j1 : (c2 ? j : j2);
            g1 = c0 ? g0 : (c1 ? f : g1);  j1 = c0 ? j0 : (c1 ? j : j1);
            g0 = c0 ? f  : g0;             j0 = c0 ? j  : j0;
        }
        const float ss = (s0 * s0 + s1 * s1) + s2 * s2;
        float d0 = ss + 2.0f * g0;
        float d1 = ss + 2.0f * g1;
        float d2 = ss + 2.0f * g2;
        float r0 = 1.0f / (d0 + 1e-8f);
        float r1 = 1.0f / (d1 + 1e-8f);
        float r2 = 1.0f / (d2 + 1e-8f);
        float s  = (r0 + r1) + r2;
        size_t base = ((size_t)b * N1_ + n1) * 3;
        wgt[base + 0] = r0 / s;  wgt[base + 1] = r1 / s;  wgt[base + 2] = r2 / s;
        idx_out[base + 0] = j0;  idx_out[base + 1] = j1;  idx_out[base + 2] = j2;
    }
}

// ---------------------------------------------------------------------------
// Kernel 2: interp_t[b][c][n] = sum_k w_k * x2[b][idx_k][c], written
// K-major (n contiguous, bf16) via an LDS transpose so the GEMM's B operand
// stages with plain vector copies.
// ---------------------------------------------------------------------------
#define TPAD 65
__global__ __launch_bounds__(256) void interp_kernel(
    const float* __restrict__ x2,
    const float* __restrict__ wgt, const int* __restrict__ idx,
    unsigned short* __restrict__ interp_t)
{
    __shared__ unsigned short tile[C2_][TPAD];   // [c][n_local]
    const int b = blockIdx.y;
    const int n0 = blockIdx.x * 64;
    const int t = threadIdx.x;
    const int w = t >> 6;     // wave id 0..3
    const int l = t & 63;     // lane

    for (int p = 0; p < 16; ++p) {
        int nl = p * 4 + w;
        size_t base = ((size_t)b * N1_ + (n0 + nl)) * 3;
        float w0 = wgt[base], w1 = wgt[base + 1], w2 = wgt[base + 2];
        int i0 = idx[base], i1 = idx[base + 1], i2 = idx[base + 2];
        const float4 va = ((const float4*)(x2 + ((size_t)b * N2_ + i0) * C2_))[l];
        const float4 vb = ((const float4*)(x2 + ((size_t)b * N2_ + i1) * C2_))[l];
        const float4 vc = ((const float4*)(x2 + ((size_t)b * N2_ + i2) * C2_))[l];
        float fa[4] = {va.x, va.y, va.z, va.w};
        float fb[4] = {vb.x, vb.y, vb.z, vb.w};
        float fc[4] = {vc.x, vc.y, vc.z, vc.w};
        #pragma unroll
        for (int i = 0; i < 4; ++i) {
            float v = w0 * fa[i];
            v = fmaf(w1, fb[i], v);
            v = fmaf(w2, fc[i], v);
            tile[l * 4 + i][nl] = f32_to_bf16_bits(v);
        }
    }
    __syncthreads();

    for (int r = 0; r < 64; ++r) {
        int c = r * 4 + w;
        interp_t[((size_t)b * C2_ + c) * K_ + n0 + l] = tile[c][l];
    }
}

// ---------------------------------------------------------------------------
// Kernel 3: per-batch GEMM  Z[b][o][c] = sum_n W1[o][n]*interp_t[b][c][n] + b1[o]
// MFMA 16x16x32 bf16. Tile 64(o) x 64(c), BK=32.
// ---------------------------------------------------------------------------
#define LDA 40
__global__ __launch_bounds__(256) void gemm_kernel(
    const unsigned short* __restrict__ W1b,
    const float* __restrict__ b1,
    const unsigned short* __restrict__ interp_t,
    float* __restrict__ Z)
{
    __shared__ unsigned short Alds[64][LDA];
    __shared__ unsigned short Blds[64][LDA];
    const int b  = blockIdx.z;
    const int o0 = blockIdx.y * 64;
    const int c0 = blockIdx.x * 64;
    const int t = threadIdx.x;
    const int w = t >> 6, l = t & 63;
    const int row = t >> 2, q = t & 3;
    const int ob = (w >> 1) * 32, cb = (w & 1) * 32;
    const int m = l & 15, kq = l >> 4;

    const unsigned short* Wp = W1b + (size_t)(o0 + row) * K_ + q * 8;
    const unsigned short* Bp = interp_t + ((size_t)b * C2_ + (c0 + row)) * K_ + q * 8;

    float4v acc[2][2] = {};

    for (int kk = 0; kk < K_; kk += 32) {
        uint4 av = *(const uint4*)(Wp + kk);
        uint4 bv = *(const uint4*)(Bp + kk);
        *(uint4*)&Alds[row][q * 8] = av;
        *(uint4*)&Blds[row][q * 8] = bv;
        __syncthreads();
        short8 a0 = *(const short8*)&Alds[ob + m][kq * 8];
        short8 a1 = *(const short8*)&Alds[ob + 16 + m][kq * 8];
        short8 b0 = *(const short8*)&Blds[cb + m][kq * 8];
        short8 b1f = *(const short8*)&Blds[cb + 16 + m][kq * 8];
        acc[0][0] = __builtin_amdgcn_mfma_f32_16x16x32_bf16(a0, b0,  acc[0][0], 0, 0, 0);
        acc[0][1] = __builtin_amdgcn_mfma_f32_16x16x32_bf16(a0, b1f, acc[0][1], 0, 0, 0);
        acc[1][0] = __builtin_amdgcn_mfma_f32_16x16x32_bf16(a1, b0,  acc[1][0], 0, 0, 0);
        acc[1][1] = __builtin_amdgcn_mfma_f32_16x16x32_bf16(a1, b1f, acc[1][1], 0, 0, 0);
        __syncthreads();
    }

    #pragma unroll
    for (int mi = 0; mi < 2; ++mi)
    #pragma unroll
    for (int ni = 0; ni < 2; ++ni)
    #pragma unroll
    for (int r = 0; r < 4; ++r) {
        int o = o0 + ob + mi * 16 + kq * 4 + r;
        int c = c0 + cb + ni * 16 + m;
        Z[((size_t)b * OUT_ + o) * C2_ + c] = acc[mi][ni][r] + b1[o];
    }
}

// ---------------------------------------------------------------------------
// Kernel 4: BN stats — per channel c, sum and sumsq over (b,o) via atomics.
// Grid 256 blocks (b x 16 o-groups of 16).
// ---------------------------------------------------------------------------
__global__ __launch_bounds__(256) void stats_kernel(
    const float* __restrict__ Z, float* __restrict__ accum)
{
    const int b  = blockIdx.x >> 4;
    const int oq = blockIdx.x & 15;
    const int c  = threadIdx.x;
    float s = 0.0f, s2 = 0.0f;
    for (int o = 0; o < 16; ++o) {
        float v = Z[((size_t)b * OUT_ + oq * 16 + o) * C2_ + c];
        s += v; s2 += v * v;
    }
    atomicAdd(&accum[c], s);
    atomicAdd(&accum[C2_ + c], s2);
}

// ---------------------------------------------------------------------------
// Kernel 5: normalize + affine + ReLU + f32 store. out has same layout as Z.
// ---------------------------------------------------------------------------
__global__ __launch_bounds__(256) void bn_kernel(
    const float* __restrict__ Z, const float* __restrict__ accum,
    const float* __restrict__ gamma, const float* __restrict__ beta,
    float* __restrict__ out)
{
    const int i = (blockIdx.x * 256 + threadIdx.x) * 4;
    float4 z = *(const float4*)(Z + i);
    float vals[4] = {z.x, z.y, z.z, z.w};
    const int cb = i & 255;
    float res[4];
    #pragma unroll
    for (int j = 0; j < 4; ++j) {
        int c = cb + j;
        float mean = accum[c] * (1.0f / 4096.0f);
        float var  = accum[C2_ + c] * (1.0f / 4096.0f) - mean * mean;
        float rstd = 1.0f / sqrtf(var + 1e-5f);
        float v = gamma[c] * ((vals[j] - mean) * rstd) + beta[c];
        res[j] = fmaxf(v, 0.0f);
    }
    *(float4*)(out + i) = make_float4(res[0], res[1], res[2], res[3]);
}

// ---------------------------------------------------------------------------
extern "C" void kernel_launch(void* const* d_in, const int* in_sizes, int n_in,
                              void* d_out, int out_size, void* d_ws, size_t ws_size,
                              hipStream_t stream) {
    const float* x2    = (const float*)d_in[1];
    const float* xyz1  = (const float*)d_in[2];
    const float* xyz2  = (const float*)d_in[3];
    const float* W1    = (const float*)d_in[4];
    const float* b1    = (const float*)d_in[5];
    const float* gamma = (const float*)d_in[6];
    const float* beta  = (const float*)d_in[7];

    char* ws = (char*)d_ws;
    float*          wgt      = (float*)(ws);                       //   786,432 B
    int*            idx      = (int*)(ws + 786432);                //   786,432 B
    unsigned short* interp_t = (unsigned short*)(ws + 1572864);    // 33,554,432 B
    unsigned short* W1b      = (unsigned short*)(ws + 35127296);   //  2,097,152 B
    float*          Z        = (float*)(ws + 37224448);            //  4,194,304 B
    float*          accum    = (float*)(ws + 41418752);            //      2,048 B

    (void)hipMemsetAsync(accum, 0, 512 * sizeof(float), stream);

    w1cvt_kernel <<<1024, 256, 0, stream>>>(W1, W1b);
    knn_kernel   <<<dim3(64, 16), 256, 0, stream>>>(xyz1, xyz2, wgt, idx);
    interp_kernel<<<dim3(64, 16), 256, 0, stream>>>(x2, wgt, idx, interp_t);
    gemm_kernel  <<<dim3(4, 4, 16), 256, 0, stream>>>(W1b, b1, interp_t, Z);
    stats_kernel <<<256, 256, 0, stream>>>(Z, accum);
    bn_kernel    <<<1024, 256, 0, stream>>>(Z, accum, gamma, beta,
                                            (float*)d_out);
}

// Round 5
// 189.377 us; speedup vs baseline: 1.4478x; 1.1206x over previous
//
#include <hip/hip_runtime.h>
#include <hip/hip_bf16.h>
#include <float.h>

#define B_    16
#define N1_   4096
#define N2_   1024
#define C2_   256
#define OUT_  256
#define K_    4096   // GEMM K == N1
#define KCH_  1024   // split-K chunk
#define ZSLAB 1048576 // floats per partial slab (16*256*256)

typedef short short8 __attribute__((ext_vector_type(8)));
typedef float float4v __attribute__((ext_vector_type(4)));

static __device__ __forceinline__ unsigned short f32_to_bf16_bits(float v) {
    __hip_bfloat16 h = __float2bfloat16(v);
    return *(unsigned short*)&h;
}

// ---------------------------------------------------------------------------
// Kernel 0: convert W1 f32 -> bf16 (1,048,576 elems) for the MFMA GEMM.
// ---------------------------------------------------------------------------
__global__ __launch_bounds__(256) void w1cvt_kernel(
    const float* __restrict__ W1, unsigned short* __restrict__ W1b)
{
    const int i = (blockIdx.x * 256 + threadIdx.x) * 4;
    float4 v = *(const float4*)(W1 + i);
    ushort4 o;
    o.x = f32_to_bf16_bits(v.x);
    o.y = f32_to_bf16_bits(v.y);
    o.z = f32_to_bf16_bits(v.z);
    o.w = f32_to_bf16_bits(v.w);
    *(ushort4*)(W1b + i) = o;
}

// ---------------------------------------------------------------------------
// Kernel 1: top-3 NN + inverse-distance weights.
// Block = 64 n1 points x 4 waves; wave w scans candidate quarter with a
// branchless per-thread top-3 on key f = 0.5*|p|^2 - dot (d = ss + 2f).
// Blocked split keeps ref earliest-index tie-break under strict '<'.
// ---------------------------------------------------------------------------
__global__ __launch_bounds__(256) void knn_kernel(
    const float* __restrict__ xyz1,
    const float* __restrict__ xyz2,
    float* __restrict__ wgt, int* __restrict__ idx_out)
{
    __shared__ float4 pts[N2_];          // (x, y, z, 0.5*|p|^2)
    __shared__ float  pf[4][64][3];
    __shared__ int    pi[4][64][3];

    const int b  = blockIdx.y;
    const int n0 = blockIdx.x * 64;
    const int t  = threadIdx.x;
    const int w  = t >> 6;
    const int l  = t & 63;

    for (int r = 0; r < 4; ++r) {
        int j = r * 256 + t;
        const float* p = xyz2 + ((size_t)b * N2_ + j) * 3;
        float x = p[0], y = p[1], z = p[2];
        pts[j] = make_float4(x, y, z, 0.5f * ((x * x + y * y) + z * z));
    }
    __syncthreads();

    const int n1 = n0 + l;
    const float* q = xyz1 + ((size_t)b * N1_ + n1) * 3;
    const float s0 = q[0], s1 = q[1], s2 = q[2];

    float f0 = FLT_MAX, f1 = FLT_MAX, f2 = FLT_MAX;
    int   i0 = 0, i1 = 0, i2 = 0;
    const int jbase = w * 256;

    #pragma unroll 4
    for (int jj = 0; jj < 256; ++jj) {
        const int j = jbase + jj;
        float4 pq = pts[j];
        float dot = s0 * pq.x;
        dot = fmaf(s1, pq.y, dot);
        dot = fmaf(s2, pq.z, dot);
        float f = pq.w - dot;
        bool c0 = f < f0, c1 = f < f1, c2 = f < f2;
        f2 = c1 ? f1 : (c2 ? f : f2);  i2 = c1 ? i1 : (c2 ? j : i2);
        f1 = c0 ? f0 : (c1 ? f : f1);  i1 = c0 ? i0 : (c1 ? j : i1);
        f0 = c0 ? f  : f0;             i0 = c0 ? j  : i0;
    }

    pf[w][l][0] = f0; pf[w][l][1] = f1; pf[w][l][2] = f2;
    pi[w][l][0] = i0; pi[w][l][1] = i1; pi[w][l][2] = i2;
    __syncthreads();

    if (w == 0) {
        float g0 = FLT_MAX, g1 = FLT_MAX, g2 = FLT_MAX;
        int   j0 = 0, j1 = 0, j2 = 0;
        #pragma unroll
        for (int p = 0; p < 4; ++p)
        #pragma unroll
        for (int r = 0; r < 3; ++r) {
            float f = pf[p][l][r];
            int   j = pi[p][l][r];
            bool c0 = f < g0, c1 = f < g1, c2 = f < g2;
            g2 = c1 ? g1 : (c2 ? f : g2);  j2 = c1 ? j1 : (c2 ? j : j2);
            g1 = c0 ? g0 : (c1 ? f : g1);  j1 = c0 ? j0 : (c1 ? j : j1);
            g0 = c0 ? f  : g0;             j0 = c0 ? j  : j0;
        }
        const float ss = (s0 * s0 + s1 * s1) + s2 * s2;
        float d0 = ss + 2.0f * g0;
        float d1 = ss + 2.0f * g1;
        float d2 = ss + 2.0f * g2;
        float r0 = 1.0f / (d0 + 1e-8f);
        float r1 = 1.0f / (d1 + 1e-8f);
        float r2 = 1.0f / (d2 + 1e-8f);
        float s  = (r0 + r1) + r2;
        size_t base = ((size_t)b * N1_ + n1) * 3;
        wgt[base + 0] = r0 / s;  wgt[base + 1] = r1 / s;  wgt[base + 2] = r2 / s;
        idx_out[base + 0] = j0;  idx_out[base + 1] = j1;  idx_out[base + 2] = j2;
    }
}

// ---------------------------------------------------------------------------
// Kernel 2: interp_t[b][c][n] = sum_k w_k * x2[b][idx_k][c]  (bf16, K-major)
// via LDS transpose.
// ---------------------------------------------------------------------------
#define TPAD 65
__global__ __launch_bounds__(256) void interp_kernel(
    const float* __restrict__ x2,
    const float* __restrict__ wgt, const int* __restrict__ idx,
    unsigned short* __restrict__ interp_t)
{
    __shared__ unsigned short tile[C2_][TPAD];   // [c][n_local]
    const int b = blockIdx.y;
    const int n0 = blockIdx.x * 64;
    const int t = threadIdx.x;
    const int w = t >> 6;
    const int l = t & 63;

    for (int p = 0; p < 16; ++p) {
        int nl = p * 4 + w;
        size_t base = ((size_t)b * N1_ + (n0 + nl)) * 3;
        float w0 = wgt[base], w1 = wgt[base + 1], w2 = wgt[base + 2];
        int i0 = idx[base], i1 = idx[base + 1], i2 = idx[base + 2];
        const float4 va = ((const float4*)(x2 + ((size_t)b * N2_ + i0) * C2_))[l];
        const float4 vb = ((const float4*)(x2 + ((size_t)b * N2_ + i1) * C2_))[l];
        const float4 vc = ((const float4*)(x2 + ((size_t)b * N2_ + i2) * C2_))[l];
        float fa[4] = {va.x, va.y, va.z, va.w};
        float fb[4] = {vb.x, vb.y, vb.z, vb.w};
        float fc[4] = {vc.x, vc.y, vc.z, vc.w};
        #pragma unroll
        for (int i = 0; i < 4; ++i) {
            float v = w0 * fa[i];
            v = fmaf(w1, fb[i], v);
            v = fmaf(w2, fc[i], v);
            tile[l * 4 + i][nl] = f32_to_bf16_bits(v);
        }
    }
    __syncthreads();

    for (int r = 0; r < 64; ++r) {
        int c = r * 4 + w;
        interp_t[((size_t)b * C2_ + c) * K_ + n0 + l] = tile[c][l];
    }
}

// ---------------------------------------------------------------------------
// Kernel 3: split-K GEMM. Partial Zp[kc][b][o][c] = sum over K-chunk kc of
// W1[o][n]*interp_t[b][c][n]. Tile 64(o) x 64(c), BK=32, 32 iters per block.
// Grid 4 x 4 x (16 b * 4 kc) = 1024 blocks -> 4 blocks/CU, 4 waves/SIMD.
// ---------------------------------------------------------------------------
#define LDA 40
__global__ __launch_bounds__(256) void gemm_kernel(
    const unsigned short* __restrict__ W1b,
    const unsigned short* __restrict__ interp_t,
    float* __restrict__ Zp)
{
    __shared__ unsigned short Alds[64][LDA];
    __shared__ unsigned short Blds[64][LDA];
    const int z  = blockIdx.z;
    const int b  = z >> 2;
    const int kc = z & 3;
    const int o0 = blockIdx.y * 64;
    const int c0 = blockIdx.x * 64;
    const int t = threadIdx.x;
    const int w = t >> 6, l = t & 63;
    const int row = t >> 2, q = t & 3;
    const int ob = (w >> 1) * 32, cb = (w & 1) * 32;
    const int m = l & 15, kq = l >> 4;

    const unsigned short* Wp = W1b + (size_t)(o0 + row) * K_ + kc * KCH_ + q * 8;
    const unsigned short* Bp = interp_t + ((size_t)b * C2_ + (c0 + row)) * K_ + kc * KCH_ + q * 8;

    float4v acc[2][2] = {};

    for (int kk = 0; kk < KCH_; kk += 32) {
        uint4 av = *(const uint4*)(Wp + kk);
        uint4 bv = *(const uint4*)(Bp + kk);
        *(uint4*)&Alds[row][q * 8] = av;
        *(uint4*)&Blds[row][q * 8] = bv;
        __syncthreads();
        short8 a0 = *(const short8*)&Alds[ob + m][kq * 8];
        short8 a1 = *(const short8*)&Alds[ob + 16 + m][kq * 8];
        short8 b0 = *(const short8*)&Blds[cb + m][kq * 8];
        short8 b1f = *(const short8*)&Blds[cb + 16 + m][kq * 8];
        acc[0][0] = __builtin_amdgcn_mfma_f32_16x16x32_bf16(a0, b0,  acc[0][0], 0, 0, 0);
        acc[0][1] = __builtin_amdgcn_mfma_f32_16x16x32_bf16(a0, b1f, acc[0][1], 0, 0, 0);
        acc[1][0] = __builtin_amdgcn_mfma_f32_16x16x32_bf16(a1, b0,  acc[1][0], 0, 0, 0);
        acc[1][1] = __builtin_amdgcn_mfma_f32_16x16x32_bf16(a1, b1f, acc[1][1], 0, 0, 0);
        __syncthreads();
    }

    float* Zslab = Zp + (size_t)kc * ZSLAB;
    #pragma unroll
    for (int mi = 0; mi < 2; ++mi)
    #pragma unroll
    for (int ni = 0; ni < 2; ++ni)
    #pragma unroll
    for (int r = 0; r < 4; ++r) {
        int o = o0 + ob + mi * 16 + kq * 4 + r;
        int c = c0 + cb + ni * 16 + m;
        Zslab[((size_t)b * OUT_ + o) * C2_ + c] = acc[mi][ni][r];
    }
}

// ---------------------------------------------------------------------------
// Kernel 4: reduce 4 partial slabs + bias -> final Z (in slab 0), and
// accumulate BN stats (sum, sumsq per channel) via one atomic pair per block.
// Grid 256 blocks = (b, oq); threads = channel c.
// ---------------------------------------------------------------------------
__global__ __launch_bounds__(256) void reduce_stats_kernel(
    float* __restrict__ Zp, const float* __restrict__ b1,
    float* __restrict__ accum)
{
    const int b  = blockIdx.x >> 4;
    const int oq = blockIdx.x & 15;
    const int c  = threadIdx.x;
    float s = 0.0f, s2 = 0.0f;
    for (int o16 = 0; o16 < 16; ++o16) {
        int o = oq * 16 + o16;
        size_t base = ((size_t)b * OUT_ + o) * C2_ + c;
        float v = Zp[base] + Zp[base + ZSLAB]
                + Zp[base + 2 * ZSLAB] + Zp[base + 3 * ZSLAB] + b1[o];
        Zp[base] = v;
        s += v; s2 += v * v;
    }
    atomicAdd(&accum[c], s);
    atomicAdd(&accum[C2_ + c], s2);
}

// ---------------------------------------------------------------------------
// Kernel 5: normalize + affine + ReLU + f32 store (reads final Z = slab 0).
// ---------------------------------------------------------------------------
__global__ __launch_bounds__(256) void bn_kernel(
    const float* __restrict__ Z, const float* __restrict__ accum,
    const float* __restrict__ gamma, const float* __restrict__ beta,
    float* __restrict__ out)
{
    const int i = (blockIdx.x * 256 + threadIdx.x) * 4;
    float4 z = *(const float4*)(Z + i);
    float vals[4] = {z.x, z.y, z.z, z.w};
    const int cb = i & 255;
    float res[4];
    #pragma unroll
    for (int j = 0; j < 4; ++j) {
        int c = cb + j;
        float mean = accum[c] * (1.0f / 4096.0f);
        float var  = accum[C2_ + c] * (1.0f / 4096.0f) - mean * mean;
        float rstd = 1.0f / sqrtf(var + 1e-5f);
        float v = gamma[c] * ((vals[j] - mean) * rstd) + beta[c];
        res[j] = fmaxf(v, 0.0f);
    }
    *(float4*)(out + i) = make_float4(res[0], res[1], res[2], res[3]);
}

// ---------------------------------------------------------------------------
extern "C" void kernel_launch(void* const* d_in, const int* in_sizes, int n_in,
                              void* d_out, int out_size, void* d_ws, size_t ws_size,
                              hipStream_t stream) {
    const float* x2    = (const float*)d_in[1];
    const float* xyz1  = (const float*)d_in[2];
    const float* xyz2  = (const float*)d_in[3];
    const float* W1    = (const float*)d_in[4];
    const float* b1    = (const float*)d_in[5];
    const float* gamma = (const float*)d_in[6];
    const float* beta  = (const float*)d_in[7];

    char* ws = (char*)d_ws;
    unsigned short* interp_t = (unsigned short*)(ws);              // 33,554,432 B
    unsigned short* W1b      = (unsigned short*)(ws + 33554432);   //  2,097,152 B
    float*          wgt      = (float*)(ws + 35651584);            //    786,432 B
    int*            idx      = (int*)(ws + 36438016);              //    786,432 B
    float*          Zp       = (float*)(ws + 37224448);            // 16,777,216 B (4 slabs)
    float*          accum    = (float*)(ws + 54001664);            //      2,048 B

    (void)hipMemsetAsync(accum, 0, 512 * sizeof(float), stream);

    w1cvt_kernel <<<1024, 256, 0, stream>>>(W1, W1b);
    knn_kernel   <<<dim3(64, 16), 256, 0, stream>>>(xyz1, xyz2, wgt, idx);
    interp_kernel<<<dim3(64, 16), 256, 0, stream>>>(x2, wgt, idx, interp_t);
    gemm_kernel  <<<dim3(4, 4, 64), 256, 0, stream>>>(W1b, interp_t, Zp);
    reduce_stats_kernel<<<256, 256, 0, stream>>>(Zp, b1, accum);
    bn_kernel    <<<1024, 256, 0, stream>>>(Zp, accum, gamma, beta,
                                            (float*)d_out);
}

// Round 6
// 172.933 us; speedup vs baseline: 1.5854x; 1.0951x over previous
//
#include <hip/hip_runtime.h>
#include <hip/hip_bf16.h>
#include <float.h>

#define B_    16
#define N1_   4096
#define N2_   1024
#define C2_   256
#define OUT_  256
#define K_    4096    // GEMM K == N1
#define SPLITK 8
#define KCH_  (K_ / SPLITK)     // 512
#define ZSLAB 1048576           // floats per partial slab (16*256*256)

typedef short short8 __attribute__((ext_vector_type(8)));
typedef float float4v __attribute__((ext_vector_type(4)));

static __device__ __forceinline__ unsigned short f32_to_bf16_bits(float v) {
    __hip_bfloat16 h = __float2bfloat16(v);
    return *(unsigned short*)&h;
}

// ---------------------------------------------------------------------------
// Kernel 0: convert W1 f32 -> bf16 (1,048,576 elems) for the MFMA GEMM.
// ---------------------------------------------------------------------------
__global__ __launch_bounds__(256) void w1cvt_kernel(
    const float* __restrict__ W1, unsigned short* __restrict__ W1b)
{
    const int i = (blockIdx.x * 256 + threadIdx.x) * 4;
    float4 v = *(const float4*)(W1 + i);
    ushort4 o;
    o.x = f32_to_bf16_bits(v.x);
    o.y = f32_to_bf16_bits(v.y);
    o.z = f32_to_bf16_bits(v.z);
    o.w = f32_to_bf16_bits(v.w);
    *(ushort4*)(W1b + i) = o;
}

// ---------------------------------------------------------------------------
// Fused Kernel 1+2: top-3 NN + inverse-distance weights + gather-interp,
// one block per 64 n1 points. Phase A (knn): 4 waves each scan a blocked
// 256-candidate quarter with branchless top-3 on key f = 0.5*|p|^2 - dot
// (d = ss + 2f; strict '<' + blocked split preserves ref earliest-index
// tie-break). Wave 0 merges, weights -> LDS. Phase B (interp): gather
// x2 rows, blend, LDS-transpose, write bf16 interp_t[b][c][n] K-major.
// LDS: union(knn 22.5KB, tile 33.3KB) + 1.5KB results = ~35KB -> 4 blk/CU.
// ---------------------------------------------------------------------------
#define TPAD 65
struct KnnSh {
    float4 pts[N2_];          // (x, y, z, 0.5*|p|^2)   16 KB
    float  pf[4][64][3];      //                         3 KB
    int    pi[4][64][3];      //                         3 KB
};
union ShUnion {
    KnnSh a;
    unsigned short tile[C2_][TPAD];   // 33.3 KB
};

__global__ __launch_bounds__(256) void knn_interp_kernel(
    const float* __restrict__ xyz1,
    const float* __restrict__ xyz2,
    const float* __restrict__ x2,
    unsigned short* __restrict__ interp_t)
{
    __shared__ ShUnion sh;
    __shared__ float rw[64][3];
    __shared__ int   ri[64][3];

    const int b  = blockIdx.y;
    const int n0 = blockIdx.x * 64;
    const int t  = threadIdx.x;
    const int w  = t >> 6;
    const int l  = t & 63;

    // ---- Phase A: knn ----
    for (int r = 0; r < 4; ++r) {
        int j = r * 256 + t;
        const float* p = xyz2 + ((size_t)b * N2_ + j) * 3;
        float x = p[0], y = p[1], z = p[2];
        sh.a.pts[j] = make_float4(x, y, z, 0.5f * ((x * x + y * y) + z * z));
    }
    __syncthreads();

    const int n1 = n0 + l;
    const float* q = xyz1 + ((size_t)b * N1_ + n1) * 3;
    const float s0 = q[0], s1 = q[1], s2 = q[2];

    float f0 = FLT_MAX, f1 = FLT_MAX, f2 = FLT_MAX;
    int   i0 = 0, i1 = 0, i2 = 0;
    const int jbase = w * 256;

    #pragma unroll 4
    for (int jj = 0; jj < 256; ++jj) {
        const int j = jbase + jj;
        float4 pq = sh.a.pts[j];
        float dot = s0 * pq.x;
        dot = fmaf(s1, pq.y, dot);
        dot = fmaf(s2, pq.z, dot);
        float f = pq.w - dot;
        bool c0 = f < f0, c1 = f < f1, c2 = f < f2;
        f2 = c1 ? f1 : (c2 ? f : f2);  i2 = c1 ? i1 : (c2 ? j : i2);
        f1 = c0 ? f0 : (c1 ? f : f1);  i1 = c0 ? i0 : (c1 ? j : i1);
        f0 = c0 ? f  : f0;             i0 = c0 ? j  : i0;
    }

    sh.a.pf[w][l][0] = f0; sh.a.pf[w][l][1] = f1; sh.a.pf[w][l][2] = f2;
    sh.a.pi[w][l][0] = i0; sh.a.pi[w][l][1] = i1; sh.a.pi[w][l][2] = i2;
    __syncthreads();

    if (w == 0) {
        float g0 = FLT_MAX, g1 = FLT_MAX, g2 = FLT_MAX;
        int   j0 = 0, j1 = 0, j2 = 0;
        #pragma unroll
        for (int p = 0; p < 4; ++p)
        #pragma unroll
        for (int r = 0; r < 3; ++r) {
            float f = sh.a.pf[p][l][r];
            int   j = sh.a.pi[p][l][r];
            bool c0 = f < g0, c1 = f < g1, c2 = f < g2;
            g2 = c1 ? g1 : (c2 ? f : g2);  j2 = c1 ? j1 : (c2 ? j : j2);
            g1 = c0 ? g0 : (c1 ? f : g1);  j1 = c0 ? j0 : (c1 ? j : j1);
            g0 = c0 ? f  : g0;             j0 = c0 ? j  : j0;
        }
        const float ss = (s0 * s0 + s1 * s1) + s2 * s2;
        float d0 = ss + 2.0f * g0;
        float d1 = ss + 2.0f * g1;
        float d2 = ss + 2.0f * g2;
        float r0 = 1.0f / (d0 + 1e-8f);
        float r1 = 1.0f / (d1 + 1e-8f);
        float r2 = 1.0f / (d2 + 1e-8f);
        float s  = (r0 + r1) + r2;
        rw[l][0] = r0 / s;  rw[l][1] = r1 / s;  rw[l][2] = r2 / s;
        ri[l][0] = j0;      ri[l][1] = j1;      ri[l][2] = j2;
    }
    __syncthreads();   // rw/ri ready; pts/pf/pi dead -> tile may alias

    // ---- Phase B: gather + blend + transpose ----
    for (int p = 0; p < 16; ++p) {
        int nl = p * 4 + w;
        float w0 = rw[nl][0], w1 = rw[nl][1], w2 = rw[nl][2];
        int i0g = ri[nl][0], i1g = ri[nl][1], i2g = ri[nl][2];
        const float4 va = ((const float4*)(x2 + ((size_t)b * N2_ + i0g) * C2_))[l];
        const float4 vb = ((const float4*)(x2 + ((size_t)b * N2_ + i1g) * C2_))[l];
        const float4 vc = ((const float4*)(x2 + ((size_t)b * N2_ + i2g) * C2_))[l];
        float fa[4] = {va.x, va.y, va.z, va.w};
        float fb[4] = {vb.x, vb.y, vb.z, vb.w};
        float fc[4] = {vc.x, vc.y, vc.z, vc.w};
        #pragma unroll
        for (int i = 0; i < 4; ++i) {
            float v = w0 * fa[i];
            v = fmaf(w1, fb[i], v);
            v = fmaf(w2, fc[i], v);
            sh.tile[l * 4 + i][nl] = f32_to_bf16_bits(v);
        }
    }
    __syncthreads();

    for (int r = 0; r < 64; ++r) {
        int c = r * 4 + w;
        interp_t[((size_t)b * C2_ + c) * K_ + n0 + l] = sh.tile[c][l];
    }
}

// ---------------------------------------------------------------------------
// Kernel 3: split-K GEMM. Zp[kc][b][o][c] partial over K-chunk kc.
// Tile 64(o) x 64(c), BK=32, KCH_/32 = 16 iters.
// Grid 4 x 4 x (16 b * 8 kc) = 2048 blocks -> 8 blocks/CU, 32 waves/CU.
// ---------------------------------------------------------------------------
#define LDA 40
__global__ __launch_bounds__(256) void gemm_kernel(
    const unsigned short* __restrict__ W1b,
    const unsigned short* __restrict__ interp_t,
    float* __restrict__ Zp)
{
    __shared__ unsigned short Alds[64][LDA];
    __shared__ unsigned short Blds[64][LDA];
    const int z  = blockIdx.z;
    const int b  = z >> 3;
    const int kc = z & 7;
    const int o0 = blockIdx.y * 64;
    const int c0 = blockIdx.x * 64;
    const int t = threadIdx.x;
    const int w = t >> 6, l = t & 63;
    const int row = t >> 2, q = t & 3;
    const int ob = (w >> 1) * 32, cb = (w & 1) * 32;
    const int m = l & 15, kq = l >> 4;

    const unsigned short* Wp = W1b + (size_t)(o0 + row) * K_ + kc * KCH_ + q * 8;
    const unsigned short* Bp = interp_t + ((size_t)b * C2_ + (c0 + row)) * K_ + kc * KCH_ + q * 8;

    float4v acc[2][2] = {};

    for (int kk = 0; kk < KCH_; kk += 32) {
        uint4 av = *(const uint4*)(Wp + kk);
        uint4 bv = *(const uint4*)(Bp + kk);
        *(uint4*)&Alds[row][q * 8] = av;
        *(uint4*)&Blds[row][q * 8] = bv;
        __syncthreads();
        short8 a0 = *(const short8*)&Alds[ob + m][kq * 8];
        short8 a1 = *(const short8*)&Alds[ob + 16 + m][kq * 8];
        short8 b0 = *(const short8*)&Blds[cb + m][kq * 8];
        short8 b1f = *(const short8*)&Blds[cb + 16 + m][kq * 8];
        acc[0][0] = __builtin_amdgcn_mfma_f32_16x16x32_bf16(a0, b0,  acc[0][0], 0, 0, 0);
        acc[0][1] = __builtin_amdgcn_mfma_f32_16x16x32_bf16(a0, b1f, acc[0][1], 0, 0, 0);
        acc[1][0] = __builtin_amdgcn_mfma_f32_16x16x32_bf16(a1, b0,  acc[1][0], 0, 0, 0);
        acc[1][1] = __builtin_amdgcn_mfma_f32_16x16x32_bf16(a1, b1f, acc[1][1], 0, 0, 0);
        __syncthreads();
    }

    float* Zslab = Zp + (size_t)kc * ZSLAB;
    #pragma unroll
    for (int mi = 0; mi < 2; ++mi)
    #pragma unroll
    for (int ni = 0; ni < 2; ++ni)
    #pragma unroll
    for (int r = 0; r < 4; ++r) {
        int o = o0 + ob + mi * 16 + kq * 4 + r;
        int c = c0 + cb + ni * 16 + m;
        Zslab[((size_t)b * OUT_ + o) * C2_ + c] = acc[mi][ni][r];
    }
}

// ---------------------------------------------------------------------------
// Kernel 4: reduce 8 partial slabs + bias -> final Z (slab 0), and
// accumulate BN stats (sum, sumsq per channel) via one atomic pair per block.
// ---------------------------------------------------------------------------
__global__ __launch_bounds__(256) void reduce_stats_kernel(
    float* __restrict__ Zp, const float* __restrict__ b1,
    float* __restrict__ accum)
{
    const int b  = blockIdx.x >> 4;
    const int oq = blockIdx.x & 15;
    const int c  = threadIdx.x;
    float s = 0.0f, s2 = 0.0f;
    for (int o16 = 0; o16 < 16; ++o16) {
        int o = oq * 16 + o16;
        size_t base = ((size_t)b * OUT_ + o) * C2_ + c;
        float v = b1[o];
        #pragma unroll
        for (int sl = 0; sl < SPLITK; ++sl)
            v += Zp[base + (size_t)sl * ZSLAB];
        Zp[base] = v;
        s += v; s2 += v * v;
    }
    atomicAdd(&accum[c], s);
    atomicAdd(&accum[C2_ + c], s2);
}

// ---------------------------------------------------------------------------
// Kernel 5: normalize + affine + ReLU + f32 store (reads final Z = slab 0).
// ---------------------------------------------------------------------------
__global__ __launch_bounds__(256) void bn_kernel(
    const float* __restrict__ Z, const float* __restrict__ accum,
    const float* __restrict__ gamma, const float* __restrict__ beta,
    float* __restrict__ out)
{
    const int i = (blockIdx.x * 256 + threadIdx.x) * 4;
    float4 z = *(const float4*)(Z + i);
    float vals[4] = {z.x, z.y, z.z, z.w};
    const int cb = i & 255;
    float res[4];
    #pragma unroll
    for (int j = 0; j < 4; ++j) {
        int c = cb + j;
        float mean = accum[c] * (1.0f / 4096.0f);
        float var  = accum[C2_ + c] * (1.0f / 4096.0f) - mean * mean;
        float rstd = 1.0f / sqrtf(var + 1e-5f);
        float v = gamma[c] * ((vals[j] - mean) * rstd) + beta[c];
        res[j] = fmaxf(v, 0.0f);
    }
    *(float4*)(out + i) = make_float4(res[0], res[1], res[2], res[3]);
}

// ---------------------------------------------------------------------------
extern "C" void kernel_launch(void* const* d_in, const int* in_sizes, int n_in,
                              void* d_out, int out_size, void* d_ws, size_t ws_size,
                              hipStream_t stream) {
    const float* x2    = (const float*)d_in[1];
    const float* xyz1  = (const float*)d_in[2];
    const float* xyz2  = (const float*)d_in[3];
    const float* W1    = (const float*)d_in[4];
    const float* b1    = (const float*)d_in[5];
    const float* gamma = (const float*)d_in[6];
    const float* beta  = (const float*)d_in[7];

    char* ws = (char*)d_ws;
    unsigned short* interp_t = (unsigned short*)(ws);              // 33,554,432 B
    unsigned short* W1b      = (unsigned short*)(ws + 33554432);   //  2,097,152 B
    float*          Zp       = (float*)(ws + 35651584);            // 33,554,432 B (8 slabs)
    float*          accum    = (float*)(ws + 69206016);            //      2,048 B

    (void)hipMemsetAsync(accum, 0, 512 * sizeof(float), stream);

    w1cvt_kernel      <<<1024, 256, 0, stream>>>(W1, W1b);
    knn_interp_kernel <<<dim3(64, 16), 256, 0, stream>>>(xyz1, xyz2, x2, interp_t);
    gemm_kernel       <<<dim3(4, 4, 128), 256, 0, stream>>>(W1b, interp_t, Zp);
    reduce_stats_kernel<<<256, 256, 0, stream>>>(Zp, b1, accum);
    bn_kernel         <<<1024, 256, 0, stream>>>(Zp, accum, gamma, beta,
                                                 (float*)d_out);
}